// Round 19
// baseline (266.401 us; speedup 1.0000x reference)
//
#include <hip/hip_runtime.h>
#include <hip/hip_bf16.h>

typedef short short8 __attribute__((ext_vector_type(8)));
typedef short short4v __attribute__((ext_vector_type(4)));
typedef unsigned short ushort8v __attribute__((ext_vector_type(8)));
typedef unsigned short ushort4v __attribute__((ext_vector_type(4)));
typedef float f32x4 __attribute__((ext_vector_type(4)));
typedef unsigned int uint32;

#define USH unsigned short

__device__ __forceinline__ USH f2bf(float f) {
  unsigned int u = __builtin_bit_cast(unsigned int, f);
  u = (u + 0x7FFFu + ((u >> 16) & 1u)) >> 16;
  return (USH)u;
}

// packed RNE f32x2 -> bf16x2 via official HIP intrinsic (verified r9/r12/r13/r15)
__device__ __forceinline__ uint32 pkbf2(float lo, float hi) {
  __hip_bfloat162 h2 = __float22bfloat162_rn(float2{lo, hi});
  uint32 r;
  __builtin_memcpy(&r, &h2, 4);
  return r;
}

__device__ __forceinline__ f32x4 mfma16(short8 a, short8 b, f32x4 c) {
  return __builtin_amdgcn_mfma_f32_16x16x32_bf16(a, b, c, 0, 0, 0);
}

// 16x16x16 bf16 MFMA (legacy K=16 shape; A/B = 4 bf16/lane at k = (lane>>4)*4+e)
__device__ __forceinline__ f32x4 mfma16h(short4v a, short4v b, f32x4 c) {
#if __has_builtin(__builtin_amdgcn_mfma_f32_16x16x16bf16_1k)
  return __builtin_amdgcn_mfma_f32_16x16x16bf16_1k(a, b, c, 0, 0, 0);
#else
  f32x4 d;
  asm volatile("v_mfma_f32_16x16x16_bf16 %0, %1, %2, %3"
               : "=&v"(d)
               : "v"(a), "v"(b), "v"(c));
  return d;
#endif
}

// async global->LDS, 16B per lane, dest = base + lane*16 (linear)
__device__ __forceinline__ void gload16(const USH* g, USH* l) {
  __builtin_amdgcn_global_load_lds(
      (const __attribute__((address_space(1))) unsigned int*)g,
      (__attribute__((address_space(3))) unsigned int*)l, 16, 0, 0);
}

__device__ __forceinline__ f32x4 vmax4(f32x4 a, f32x4 b) {
  f32x4 r;
  r[0] = fmaxf(a[0], b[0]);
  r[1] = fmaxf(a[1], b[1]);
  r[2] = fmaxf(a[2], b[2]);
  r[3] = fmaxf(a[3], b[3]);
  return r;
}

union Frag4 {
  uint32 u[2];
  short4v s4;
};

// ---------------- fp32 -> bf16 convert ----------------
__global__ __launch_bounds__(256) void cvt_bf16(const float* __restrict__ in,
                                                USH* __restrict__ out, int n4) {
  int i = blockIdx.x * 256 + threadIdx.x;
  if (i >= n4) return;
  f32x4 v = *(const f32x4*)(in + (size_t)i * 4);
  ushort4v o;
#pragma unroll
  for (int k = 0; k < 4; k++) o[k] = f2bf(v[k]);
  *(ushort4v*)(out + (size_t)i * 4) = o;
}

// ---------------- GEMM: C[M,N] = A[M,K] @ B[N,K]^T + bias ----------------
template <bool OUT_F32>
__global__ __launch_bounds__(256) void gemm_bt(const USH* __restrict__ A,
                                               const USH* __restrict__ B,
                                               const float* __restrict__ bias,
                                               void* __restrict__ Cout,
                                               int M, int N, int K) {
  __shared__ __align__(16) USH As[128 * 64];
  __shared__ __align__(16) USH Bs[128 * 64];
  const int tid = threadIdx.x;
  const int row0 = blockIdx.x * 128;
  const int col0 = blockIdx.y * 128;
  const int wid = tid >> 6, lane = tid & 63;
  const int wr = (wid >> 1) * 64, wc = (wid & 1) * 64;
  const int lmod = lane & 15, ldiv = lane >> 4;
  const int asw = lmod & 7;
  const int srow = lane >> 3;
  const int scol = ((lane & 7) ^ srow) * 8;

  f32x4 acc[4][4];
#pragma unroll
  for (int i = 0; i < 4; i++)
#pragma unroll
    for (int j = 0; j < 4; j++) acc[i][j] = (f32x4){0.f, 0.f, 0.f, 0.f};

  const USH* Ab = A + (size_t)row0 * K;
  const USH* Bb = B + (size_t)col0 * K;

  for (int k0 = 0; k0 < K; k0 += 64) {
    __syncthreads();
#pragma unroll
    for (int i = 0; i < 4; i++) {
      int r0 = wid * 32 + i * 8;
      int r = r0 + srow;
      gload16(&Ab[(size_t)r * K + k0 + scol], &As[r0 * 64]);
      gload16(&Bb[(size_t)r * K + k0 + scol], &Bs[r0 * 64]);
    }
    __syncthreads();
#pragma unroll
    for (int kk = 0; kk < 64; kk += 32) {
      short8 a[4], b[4];
#pragma unroll
      for (int i = 0; i < 4; i++)
        a[i] = *(const short8*)&As[(wr + i * 16 + lmod) * 64 +
                                   ((((kk >> 3) + ldiv) ^ asw) << 3)];
#pragma unroll
      for (int i = 0; i < 4; i++)
        b[i] = *(const short8*)&Bs[(wc + i * 16 + lmod) * 64 +
                                   ((((kk >> 3) + ldiv) ^ asw) << 3)];
#pragma unroll
      for (int i = 0; i < 4; i++)
#pragma unroll
        for (int j = 0; j < 4; j++)
          acc[i][j] = mfma16(a[i], b[j], acc[i][j]);
    }
  }

  const int r4 = ldiv * 4;
#pragma unroll
  for (int i = 0; i < 4; i++) {
#pragma unroll
    for (int j = 0; j < 4; j++) {
      int rr = row0 + wr + i * 16 + r4;
      int cc = col0 + wc + j * 16 + lmod;
      float bv = bias[cc];
#pragma unroll
      for (int t = 0; t < 4; t++) {
        float v = acc[i][j][t] + bv;
        if (OUT_F32)
          ((float*)Cout)[(size_t)(rr + t) * N + cc] = v;
        else
          ((USH*)Cout)[(size_t)(rr + t) * N + cc] = f2bf(v);
      }
    }
  }
}

// ---------------- V transpose ----------------
__global__ __launch_bounds__(256) void vtrans(const USH* __restrict__ qkv,
                                              USH* __restrict__ vT) {
  __shared__ __align__(16) USH t[64][72];
  const int bh = blockIdx.y, b = bh >> 3, h = bh & 7;
  const int s0 = blockIdx.x * 64;
  const int tid = threadIdx.x;
  const int r = tid >> 4, c4 = (tid & 15) * 4;
#pragma unroll
  for (int i = 0; i < 4; i++) {
    int row = r + i * 16;
    *(ushort4v*)&t[row][c4] =
        *(const ushort4v*)&qkv[(size_t)(b * 4096 + s0 + row) * 1536 + 1024 + h * 64 + c4];
  }
  __syncthreads();
  const int d = tid >> 2, sb = (tid & 3) * 16;
  size_t ob = (size_t)(bh * 64 + d) * 4096 + s0 + sb;
#pragma unroll
  for (int half = 0; half < 2; half++) {
    ushort8v o;
#pragma unroll
    for (int k = 0; k < 8; k++) o[k] = t[sb + half * 8 + k][d];
    *(ushort8v*)&vT[ob + half * 8] = o;
  }
}

// ---------------- Flash attention v19: r17 math, t=0 peeled via macro, unroll-2 hint ----------------
__global__ __launch_bounds__(256, 4) void attn_fwd(const USH* __restrict__ qkv,
                                                   const USH* __restrict__ vT,
                                                   USH* __restrict__ attno) {
  __shared__ __align__(16) USH Ks[2][64 * 64];  // 16 KB
  __shared__ __align__(16) USH Vs[2][64 * 64];  // 16 KB

  const int fb = blockIdx.x;
  const int b3 = fb & 7;
  const int rest = fb >> 3;
  const int qb = rest & 31;
  const int bh = b3 + 8 * (rest >> 5);
  const int b = bh >> 3, h = bh & 7;

  const int wid = threadIdx.x >> 6, lane = threadIdx.x & 63;
  const int lmod = lane & 15, ldiv = lane >> 4;
  const int ksw = lmod & 7;
  const int qrow0 = qb * 128 + wid * 32;

  short8 qf00, qf01, qf10, qf11;
  {
    const USH* qp = qkv + (size_t)(b * 4096 + qrow0 + lmod) * 1536 + h * 64 + ldiv * 8;
    qf00 = *(const short8*)qp;
    qf01 = *(const short8*)(qp + 32);
    qp += (size_t)16 * 1536;
    qf10 = *(const short8*)qp;
    qf11 = *(const short8*)(qp + 32);
  }

  short4v ones4;
#pragma unroll
  for (int i = 0; i < 4; i++) ones4[i] = (short)0x3F80;  // bf16 1.0

  f32x4 acc0[4], acc1[4];
#pragma unroll
  for (int n = 0; n < 4; n++) {
    acc0[n] = (f32x4){0.f, 0.f, 0.f, 0.f};
    acc1[n] = (f32x4){0.f, 0.f, 0.f, 0.f};
  }
  f32x4 l0 = (f32x4){0.f, 0.f, 0.f, 0.f}, l1 = l0;
  float nmk0 = 0.f, nmk1 = 0.f;  // -m*K2, m fixed from tile 0 (r17-verified exact)
  const f32x4 z4 = (f32x4){0.f, 0.f, 0.f, 0.f};

  const USH* kbase = qkv + (size_t)b * 4096 * 1536 + 512 + h * 64;
  const USH* vbase = vT + (size_t)bh * 64 * 4096;
  const int srow = lane >> 3;
  const int scol = ((lane & 7) ^ srow) * 8;
  const float K2 = 0.18033688011112042f;  // log2(e)/8

  auto stage = [&](int bu, int k0) {
#pragma unroll
    for (int i = 0; i < 2; ++i) {
      int r0 = wid * 16 + i * 8;
      int r = r0 + srow;
      gload16(kbase + (size_t)(k0 + r) * 1536 + scol, &Ks[bu][r0 * 64]);
      int vsw = ((2 * (lane & 7)) ^ (r & 14)) * 4;
      gload16(vbase + (size_t)r * 4096 + k0 + vsw, &Vs[bu][r0 * 64]);
    }
  };

  // Body macro: pure textual inline, no struct, no ABI. FIRSTF is a literal.
#define ATTN_BODY(KC, VC, FIRSTF)                                              \
  do {                                                                         \
    const USH* Kc_ = (KC);                                                     \
    const USH* Vc_ = (VC);                                                     \
    f32x4 s0[4], s1[4];                                                        \
    __builtin_amdgcn_s_setprio(1);                                             \
    _Pragma("unroll") for (int n = 0; n < 4; n++) {                            \
      const USH* kr = Kc_ + (n * 16 + lmod) * 64;                              \
      short8 kf0 = *(const short8*)(kr + ((ldiv ^ ksw) << 3));                 \
      short8 kf1 = *(const short8*)(kr + (((4 + ldiv) ^ ksw) << 3));           \
      s0[n] = mfma16(kf0, qf00, z4);                                           \
      s0[n] = mfma16(kf1, qf01, s0[n]);                                        \
      s1[n] = mfma16(kf0, qf10, z4);                                           \
      s1[n] = mfma16(kf1, qf11, s1[n]);                                        \
    }                                                                          \
    __builtin_amdgcn_s_setprio(0);                                             \
    if (FIRSTF) {                                                              \
      f32x4 u0 = vmax4(vmax4(s0[0], s0[1]), vmax4(s0[2], s0[3]));              \
      float p0 = fmaxf(fmaxf(u0[0], u0[1]), fmaxf(u0[2], u0[3]));              \
      p0 = fmaxf(p0, __shfl_xor(p0, 16));                                      \
      p0 = fmaxf(p0, __shfl_xor(p0, 32));                                      \
      f32x4 u1 = vmax4(vmax4(s1[0], s1[1]), vmax4(s1[2], s1[3]));              \
      float p1 = fmaxf(fmaxf(u1[0], u1[1]), fmaxf(u1[2], u1[3]));              \
      p1 = fmaxf(p1, __shfl_xor(p1, 16));                                      \
      p1 = fmaxf(p1, __shfl_xor(p1, 32));                                      \
      nmk0 = -p0 * K2;                                                         \
      nmk1 = -p1 * K2;                                                         \
    }                                                                          \
    _Pragma("unroll") for (int n = 0; n < 4; n++) {                            \
      Frag4 pa0, pa1;                                                          \
      {                                                                        \
        float e0 = __builtin_amdgcn_exp2f(fmaf(s0[n][0], K2, nmk0));           \
        float e1 = __builtin_amdgcn_exp2f(fmaf(s0[n][1], K2, nmk0));           \
        float e2 = __builtin_amdgcn_exp2f(fmaf(s0[n][2], K2, nmk0));           \
        float e3 = __builtin_amdgcn_exp2f(fmaf(s0[n][3], K2, nmk0));           \
        pa0.u[0] = pkbf2(e0, e1);                                              \
        pa0.u[1] = pkbf2(e2, e3);                                              \
      }                                                                        \
      {                                                                        \
        float e0 = __builtin_amdgcn_exp2f(fmaf(s1[n][0], K2, nmk1));           \
        float e1 = __builtin_amdgcn_exp2f(fmaf(s1[n][1], K2, nmk1));           \
        float e2 = __builtin_amdgcn_exp2f(fmaf(s1[n][2], K2, nmk1));           \
        float e3 = __builtin_amdgcn_exp2f(fmaf(s1[n][3], K2, nmk1));           \
        pa1.u[0] = pkbf2(e0, e1);                                              \
        pa1.u[1] = pkbf2(e2, e3);                                              \
      }                                                                        \
      __builtin_amdgcn_s_setprio(1);                                           \
      l0 = mfma16h(pa0.s4, ones4, l0);                                         \
      l1 = mfma16h(pa1.s4, ones4, l1);                                         \
      _Pragma("unroll") for (int n2 = 0; n2 < 4; n2++) {                       \
        const int vcol = (((n * 4 + ldiv) ^ (lmod & 14)) << 2);                \
        short4v vf = *(const short4v*)(Vc_ + (n2 * 16 + lmod) * 64 + vcol);    \
        acc0[n2] = mfma16h(pa0.s4, vf, acc0[n2]);                              \
        acc1[n2] = mfma16h(pa1.s4, vf, acc1[n2]);                              \
      }                                                                        \
      __builtin_amdgcn_s_setprio(0);                                           \
    }                                                                          \
  } while (0)

  stage(0, 0);

  // t = 0 peeled (computes nmk); steady-state loop has no FIRST branch
  __syncthreads();
  stage(1, 64);
  ATTN_BODY(&Ks[0][0], &Vs[0][0], 1);

#pragma unroll 2
  for (int t = 1; t < 64; ++t) {
    const int cur = t & 1;
    __syncthreads();
    if (t < 63) stage(cur ^ 1, (t + 1) * 64);
    ATTN_BODY(&Ks[cur][0], &Vs[cur][0], 0);
  }
#undef ATTN_BODY

  // ---- epilogue (acc layout: q = ldiv*4+j, dh = n*16+lmod) ----
  float iv0[4], iv1[4];
#pragma unroll
  for (int j = 0; j < 4; j++) {
    iv0[j] = 1.0f / l0[j];
    iv1[j] = 1.0f / l1[j];
  }
  USH* ob = attno + (size_t)(b * 4096 + qrow0) * 512 + h * 64;
#pragma unroll
  for (int n = 0; n < 4; n++) {
#pragma unroll
    for (int j = 0; j < 4; j++) {
      ob[(size_t)(ldiv * 4 + j) * 512 + n * 16 + lmod] = f2bf(acc0[n][j] * iv0[j]);
      ob[(size_t)(16 + ldiv * 4 + j) * 512 + n * 16 + lmod] = f2bf(acc1[n][j] * iv1[j]);
    }
  }
}

// ---------------- launch ----------------
extern "C" void kernel_launch(void* const* d_in, const int* in_sizes, int n_in,
                              void* d_out, int out_size, void* d_ws, size_t ws_size,
                              hipStream_t stream) {
  const float* x = (const float*)d_in[0];      // (4,4096,512)
  const float* w_in = (const float*)d_in[1];   // (1536,512)
  const float* b_in = (const float*)d_in[2];   // (1536)
  const float* w_out = (const float*)d_in[3];  // (512,512)
  const float* b_out = (const float*)d_in[4];  // (512)
  float* out = (float*)d_out;                  // (4,4096,512) fp32

  char* ws = (char*)d_ws;
  USH* xb = (USH*)(ws);                        // 16 MB (reused as attno later)
  USH* winb = (USH*)(ws + 16777216);           // 1.5 MB
  USH* woutb = (USH*)(ws + 18350080);          // 0.5 MB
  USH* qkv = (USH*)(ws + 18874368);            // 48 MB
  USH* vT = (USH*)(ws + 69206016);             // 16 MB
  USH* attno = xb;                             // alias: xb dead after gemm1

  cvt_bf16<<<8192, 256, 0, stream>>>(x, xb, 2097152);
  cvt_bf16<<<768, 256, 0, stream>>>(w_in, winb, 196608);
  cvt_bf16<<<256, 256, 0, stream>>>(w_out, woutb, 65536);

  gemm_bt<false><<<dim3(128, 12), 256, 0, stream>>>(xb, winb, b_in, qkv, 16384, 1536, 512);
  vtrans<<<dim3(64, 32), 256, 0, stream>>>(qkv, vT);
  attn_fwd<<<1024, 256, 0, stream>>>(qkv, vT, attno);
  gemm_bt<true><<<dim3(128, 4), 256, 0, stream>>>(attno, woutb, b_out, out, 16384, 512, 512);
}

// Round 20
// 246.904 us; speedup vs baseline: 1.0790x; 1.0790x over previous
//
#include <hip/hip_runtime.h>
#include <hip/hip_bf16.h>

typedef short short8 __attribute__((ext_vector_type(8)));
typedef short short4v __attribute__((ext_vector_type(4)));
typedef unsigned short ushort8v __attribute__((ext_vector_type(8)));
typedef unsigned short ushort4v __attribute__((ext_vector_type(4)));
typedef float f32x4 __attribute__((ext_vector_type(4)));
typedef unsigned int uint32;

#define USH unsigned short

__device__ __forceinline__ USH f2bf(float f) {
  unsigned int u = __builtin_bit_cast(unsigned int, f);
  u = (u + 0x7FFFu + ((u >> 16) & 1u)) >> 16;
  return (USH)u;
}

// packed RNE f32x2 -> bf16x2 via official HIP intrinsic (verified r9/r12/r13/r15/r17)
__device__ __forceinline__ uint32 pkbf2(float lo, float hi) {
  __hip_bfloat162 h2 = __float22bfloat162_rn(float2{lo, hi});
  uint32 r;
  __builtin_memcpy(&r, &h2, 4);
  return r;
}

__device__ __forceinline__ f32x4 mfma16(short8 a, short8 b, f32x4 c) {
  return __builtin_amdgcn_mfma_f32_16x16x32_bf16(a, b, c, 0, 0, 0);
}

// 16x16x16 bf16 MFMA (legacy K=16 shape; A/B = 4 bf16/lane at k = (lane>>4)*4+e)
__device__ __forceinline__ f32x4 mfma16h(short4v a, short4v b, f32x4 c) {
#if __has_builtin(__builtin_amdgcn_mfma_f32_16x16x16bf16_1k)
  return __builtin_amdgcn_mfma_f32_16x16x16bf16_1k(a, b, c, 0, 0, 0);
#else
  f32x4 d;
  asm volatile("v_mfma_f32_16x16x16_bf16 %0, %1, %2, %3"
               : "=&v"(d)
               : "v"(a), "v"(b), "v"(c));
  return d;
#endif
}

// async global->LDS, 16B per lane, dest = base + lane*16 (linear)
__device__ __forceinline__ void gload16(const USH* g, USH* l) {
  __builtin_amdgcn_global_load_lds(
      (const __attribute__((address_space(1))) unsigned int*)g,
      (__attribute__((address_space(3))) unsigned int*)l, 16, 0, 0);
}

__device__ __forceinline__ f32x4 vmax4(f32x4 a, f32x4 b) {
  f32x4 r;
  r[0] = fmaxf(a[0], b[0]);
  r[1] = fmaxf(a[1], b[1]);
  r[2] = fmaxf(a[2], b[2]);
  r[3] = fmaxf(a[3], b[3]);
  return r;
}

union Frag4 {
  uint32 u[2];
  short4v s4;
};

// ---------------- fp32 -> bf16 convert (all three inputs, one launch) ----------------
// grid = 9216: [0,8192) -> x (2097152 float4), [8192,8960) -> w_in (196608),
// [8960,9216) -> w_out (65536). All ranges are exact multiples of 256.
__global__ __launch_bounds__(256) void cvt_all(const float* __restrict__ x,
                                               const float* __restrict__ w_in,
                                               const float* __restrict__ w_out,
                                               USH* __restrict__ xb,
                                               USH* __restrict__ winb,
                                               USH* __restrict__ woutb) {
  const int bid = blockIdx.x;
  const float* src;
  USH* dst;
  int i;
  if (bid < 8192) {
    src = x;
    dst = xb;
    i = bid * 256 + threadIdx.x;
  } else if (bid < 8960) {
    src = w_in;
    dst = winb;
    i = (bid - 8192) * 256 + threadIdx.x;
  } else {
    src = w_out;
    dst = woutb;
    i = (bid - 8960) * 256 + threadIdx.x;
  }
  f32x4 v = *(const f32x4*)(src + (size_t)i * 4);
  ushort4v o;
#pragma unroll
  for (int k = 0; k < 4; k++) o[k] = f2bf(v[k]);
  *(ushort4v*)(dst + (size_t)i * 4) = o;
}

// ---------------- GEMM: C[M,N] = A[M,K] @ B[N,K]^T + bias ----------------
template <bool OUT_F32>
__global__ __launch_bounds__(256) void gemm_bt(const USH* __restrict__ A,
                                               const USH* __restrict__ B,
                                               const float* __restrict__ bias,
                                               void* __restrict__ Cout,
                                               int M, int N, int K) {
  __shared__ __align__(16) USH As[128 * 64];
  __shared__ __align__(16) USH Bs[128 * 64];
  const int tid = threadIdx.x;
  const int row0 = blockIdx.x * 128;
  const int col0 = blockIdx.y * 128;
  const int wid = tid >> 6, lane = tid & 63;
  const int wr = (wid >> 1) * 64, wc = (wid & 1) * 64;
  const int lmod = lane & 15, ldiv = lane >> 4;
  const int asw = lmod & 7;
  const int srow = lane >> 3;
  const int scol = ((lane & 7) ^ srow) * 8;

  f32x4 acc[4][4];
#pragma unroll
  for (int i = 0; i < 4; i++)
#pragma unroll
    for (int j = 0; j < 4; j++) acc[i][j] = (f32x4){0.f, 0.f, 0.f, 0.f};

  const USH* Ab = A + (size_t)row0 * K;
  const USH* Bb = B + (size_t)col0 * K;

  for (int k0 = 0; k0 < K; k0 += 64) {
    __syncthreads();
#pragma unroll
    for (int i = 0; i < 4; i++) {
      int r0 = wid * 32 + i * 8;
      int r = r0 + srow;
      gload16(&Ab[(size_t)r * K + k0 + scol], &As[r0 * 64]);
      gload16(&Bb[(size_t)r * K + k0 + scol], &Bs[r0 * 64]);
    }
    __syncthreads();
#pragma unroll
    for (int kk = 0; kk < 64; kk += 32) {
      short8 a[4], b[4];
#pragma unroll
      for (int i = 0; i < 4; i++)
        a[i] = *(const short8*)&As[(wr + i * 16 + lmod) * 64 +
                                   ((((kk >> 3) + ldiv) ^ asw) << 3)];
#pragma unroll
      for (int i = 0; i < 4; i++)
        b[i] = *(const short8*)&Bs[(wc + i * 16 + lmod) * 64 +
                                   ((((kk >> 3) + ldiv) ^ asw) << 3)];
#pragma unroll
      for (int i = 0; i < 4; i++)
#pragma unroll
        for (int j = 0; j < 4; j++)
          acc[i][j] = mfma16(a[i], b[j], acc[i][j]);
    }
  }

  const int r4 = ldiv * 4;
#pragma unroll
  for (int i = 0; i < 4; i++) {
#pragma unroll
    for (int j = 0; j < 4; j++) {
      int rr = row0 + wr + i * 16 + r4;
      int cc = col0 + wc + j * 16 + lmod;
      float bv = bias[cc];
#pragma unroll
      for (int t = 0; t < 4; t++) {
        float v = acc[i][j][t] + bv;
        if (OUT_F32)
          ((float*)Cout)[(size_t)(rr + t) * N + cc] = v;
        else
          ((USH*)Cout)[(size_t)(rr + t) * N + cc] = f2bf(v);
      }
    }
  }
}

// ---------------- V transpose ----------------
__global__ __launch_bounds__(256) void vtrans(const USH* __restrict__ qkv,
                                              USH* __restrict__ vT) {
  __shared__ __align__(16) USH t[64][72];
  const int bh = blockIdx.y, b = bh >> 3, h = bh & 7;
  const int s0 = blockIdx.x * 64;
  const int tid = threadIdx.x;
  const int r = tid >> 4, c4 = (tid & 15) * 4;
#pragma unroll
  for (int i = 0; i < 4; i++) {
    int row = r + i * 16;
    *(ushort4v*)&t[row][c4] =
        *(const ushort4v*)&qkv[(size_t)(b * 4096 + s0 + row) * 1536 + 1024 + h * 64 + c4];
  }
  __syncthreads();
  const int d = tid >> 2, sb = (tid & 3) * 16;
  size_t ob = (size_t)(bh * 64 + d) * 4096 + s0 + sb;
#pragma unroll
  for (int half = 0; half < 2; half++) {
    ushort8v o;
#pragma unroll
    for (int k = 0; k < 8; k++) o[k] = t[sb + half * 8 + k][d];
    *(ushort8v*)&vT[ob + half * 8] = o;
  }
}

// ---------------- Flash attention v20 == v17 (best verified: 195.5 us) ----------------
__global__ __launch_bounds__(256, 4) void attn_fwd(const USH* __restrict__ qkv,
                                                   const USH* __restrict__ vT,
                                                   USH* __restrict__ attno) {
  __shared__ __align__(16) USH Ks[2][64 * 64];   // 16 KB
  __shared__ __align__(16) USH Vs[2][64 * 64];   // 16 KB

  const int fb = blockIdx.x;
  const int b3 = fb & 7;
  const int rest = fb >> 3;
  const int qb = rest & 31;
  const int bh = b3 + 8 * (rest >> 5);
  const int b = bh >> 3, h = bh & 7;

  const int wid = threadIdx.x >> 6, lane = threadIdx.x & 63;
  const int lmod = lane & 15, ldiv = lane >> 4;
  const int ksw = lmod & 7;
  const int qrow0 = qb * 128 + wid * 32;

  short8 qf00, qf01, qf10, qf11;
  {
    const USH* qp = qkv + (size_t)(b * 4096 + qrow0 + lmod) * 1536 + h * 64 + ldiv * 8;
    qf00 = *(const short8*)qp;
    qf01 = *(const short8*)(qp + 32);
    qp += (size_t)16 * 1536;
    qf10 = *(const short8*)qp;
    qf11 = *(const short8*)(qp + 32);
  }

  short4v ones4;
#pragma unroll
  for (int i = 0; i < 4; i++) ones4[i] = (short)0x3F80;  // bf16 1.0

  f32x4 acc0[4], acc1[4];
#pragma unroll
  for (int n = 0; n < 4; n++) {
    acc0[n] = (f32x4){0.f, 0.f, 0.f, 0.f};
    acc1[n] = (f32x4){0.f, 0.f, 0.f, 0.f};
  }
  f32x4 l0 = (f32x4){0.f, 0.f, 0.f, 0.f}, l1 = l0;
  float nmk0 = 0.f, nmk1 = 0.f;  // -m*K2, m fixed from tile 0 (r17-verified exact)
  const f32x4 z4 = (f32x4){0.f, 0.f, 0.f, 0.f};

  const USH* kbase = qkv + (size_t)b * 4096 * 1536 + 512 + h * 64;
  const USH* vbase = vT + (size_t)bh * 64 * 4096;
  const int srow = lane >> 3;
  const int scol = ((lane & 7) ^ srow) * 8;  // K source swizzle (8-group, row&7)
  const float K2 = 0.18033688011112042f;     // log2(e)/8

  auto stage = [&](int bu, int k0) {
#pragma unroll
    for (int i = 0; i < 2; ++i) {
      int r0 = wid * 16 + i * 8;
      int r = r0 + srow;
      gload16(kbase + (size_t)(k0 + r) * 1536 + scol, &Ks[bu][r0 * 64]);
      // V: 4-USH-granular XOR with (row&14); even mask keeps 16B source contiguous.
      int vsw = ((2 * (lane & 7)) ^ (r & 14)) * 4;
      gload16(vbase + (size_t)r * 4096 + k0 + vsw, &Vs[bu][r0 * 64]);
    }
  };

  stage(0, 0);

  for (int t = 0; t < 64; ++t) {
    const int cur = t & 1;
    __syncthreads();
    if (t < 63) stage(cur ^ 1, (t + 1) * 64);

    const USH* Kc = &Ks[cur][0];
    const USH* Vc = &Vs[cur][0];

    // ---- QK^T swapped: s{0,1}[n][j] -> q = lmod, kv = n*16 + ldiv*4 + j ----
    f32x4 s0[4], s1[4];
    __builtin_amdgcn_s_setprio(1);
#pragma unroll
    for (int n = 0; n < 4; n++) {
      const USH* kr = Kc + (n * 16 + lmod) * 64;
      short8 kf0 = *(const short8*)(kr + ((ldiv ^ ksw) << 3));
      short8 kf1 = *(const short8*)(kr + (((4 + ldiv) ^ ksw) << 3));
      s0[n] = mfma16(kf0, qf00, z4);
      s0[n] = mfma16(kf1, qf01, s0[n]);
      s1[n] = mfma16(kf0, qf10, z4);
      s1[n] = mfma16(kf1, qf11, s1[n]);
    }
    __builtin_amdgcn_s_setprio(0);

    // ---- m fixed at tile 0 (full row-max); exact (m-invariant math, r17) ----
    if (t == 0) {
      f32x4 u0 = vmax4(vmax4(s0[0], s0[1]), vmax4(s0[2], s0[3]));
      float p0 = fmaxf(fmaxf(u0[0], u0[1]), fmaxf(u0[2], u0[3]));
      p0 = fmaxf(p0, __shfl_xor(p0, 16));
      p0 = fmaxf(p0, __shfl_xor(p0, 32));
      f32x4 u1 = vmax4(vmax4(s1[0], s1[1]), vmax4(s1[2], s1[3]));
      float p1 = fmaxf(fmaxf(u1[0], u1[1]), fmaxf(u1[2], u1[3]));
      p1 = fmaxf(p1, __shfl_xor(p1, 16));
      p1 = fmaxf(p1, __shfl_xor(p1, 32));
      nmk0 = -p0 * K2;
      nmk1 = -p1 * K2;
    }

    // ---- P in-register -> 16x16x16 PV (+ rowsum); V fragment shared by both groups ----
#pragma unroll
    for (int n = 0; n < 4; n++) {
      Frag4 pa0, pa1;
      {
        float e0 = __builtin_amdgcn_exp2f(fmaf(s0[n][0], K2, nmk0));
        float e1 = __builtin_amdgcn_exp2f(fmaf(s0[n][1], K2, nmk0));
        float e2 = __builtin_amdgcn_exp2f(fmaf(s0[n][2], K2, nmk0));
        float e3 = __builtin_amdgcn_exp2f(fmaf(s0[n][3], K2, nmk0));
        pa0.u[0] = pkbf2(e0, e1);
        pa0.u[1] = pkbf2(e2, e3);
      }
      {
        float e0 = __builtin_amdgcn_exp2f(fmaf(s1[n][0], K2, nmk1));
        float e1 = __builtin_amdgcn_exp2f(fmaf(s1[n][1], K2, nmk1));
        float e2 = __builtin_amdgcn_exp2f(fmaf(s1[n][2], K2, nmk1));
        float e3 = __builtin_amdgcn_exp2f(fmaf(s1[n][3], K2, nmk1));
        pa1.u[0] = pkbf2(e0, e1);
        pa1.u[1] = pkbf2(e2, e3);
      }
      __builtin_amdgcn_s_setprio(1);
      l0 = mfma16h(pa0.s4, ones4, l0);
      l1 = mfma16h(pa1.s4, ones4, l1);
#pragma unroll
      for (int n2 = 0; n2 < 4; n2++) {
        // V read: stored c4' = (n*4+ldiv) ^ (row&14), row = n2*16+lmod
        const int vcol = (((n * 4 + ldiv) ^ (lmod & 14)) << 2);
        short4v vf = *(const short4v*)(Vc + (n2 * 16 + lmod) * 64 + vcol);
        acc0[n2] = mfma16h(pa0.s4, vf, acc0[n2]);
        acc1[n2] = mfma16h(pa1.s4, vf, acc1[n2]);
      }
      __builtin_amdgcn_s_setprio(0);
    }
  }

  // ---- epilogue (acc layout: q = ldiv*4+j, dh = n*16+lmod) ----
  float iv0[4], iv1[4];
#pragma unroll
  for (int j = 0; j < 4; j++) {
    iv0[j] = 1.0f / l0[j];
    iv1[j] = 1.0f / l1[j];
  }
  USH* ob = attno + (size_t)(b * 4096 + qrow0) * 512 + h * 64;
#pragma unroll
  for (int n = 0; n < 4; n++) {
#pragma unroll
    for (int j = 0; j < 4; j++) {
      ob[(size_t)(ldiv * 4 + j) * 512 + n * 16 + lmod] = f2bf(acc0[n][j] * iv0[j]);
      ob[(size_t)(16 + ldiv * 4 + j) * 512 + n * 16 + lmod] = f2bf(acc1[n][j] * iv1[j]);
    }
  }
}

// ---------------- launch ----------------
extern "C" void kernel_launch(void* const* d_in, const int* in_sizes, int n_in,
                              void* d_out, int out_size, void* d_ws, size_t ws_size,
                              hipStream_t stream) {
  const float* x = (const float*)d_in[0];      // (4,4096,512)
  const float* w_in = (const float*)d_in[1];   // (1536,512)
  const float* b_in = (const float*)d_in[2];   // (1536)
  const float* w_out = (const float*)d_in[3];  // (512,512)
  const float* b_out = (const float*)d_in[4];  // (512)
  float* out = (float*)d_out;                  // (4,4096,512) fp32

  char* ws = (char*)d_ws;
  USH* xb = (USH*)(ws);                        // 16 MB (reused as attno later)
  USH* winb = (USH*)(ws + 16777216);           // 1.5 MB
  USH* woutb = (USH*)(ws + 18350080);          // 0.5 MB
  USH* qkv = (USH*)(ws + 18874368);            // 48 MB
  USH* vT = (USH*)(ws + 69206016);             // 16 MB
  USH* attno = xb;                             // alias: xb dead after gemm1

  cvt_all<<<9216, 256, 0, stream>>>(x, w_in, w_out, xb, winb, woutb);

  gemm_bt<false><<<dim3(128, 12), 256, 0, stream>>>(xb, winb, b_in, qkv, 16384, 1536, 512);
  vtrans<<<dim3(64, 32), 256, 0, stream>>>(qkv, vT);
  attn_fwd<<<1024, 256, 0, stream>>>(qkv, vT, attno);
  gemm_bt<true><<<dim3(128, 4), 256, 0, stream>>>(attno, woutb, b_out, out, 16384, 512, 512);
}

// Round 21
// 238.460 us; speedup vs baseline: 1.1172x; 1.0354x over previous
//
#include <hip/hip_runtime.h>
#include <hip/hip_bf16.h>

typedef short short8 __attribute__((ext_vector_type(8)));
typedef short short4v __attribute__((ext_vector_type(4)));
typedef unsigned short ushort8v __attribute__((ext_vector_type(8)));
typedef unsigned short ushort4v __attribute__((ext_vector_type(4)));
typedef float f32x4 __attribute__((ext_vector_type(4)));
typedef unsigned int uint32;

#define USH unsigned short

__device__ __forceinline__ USH f2bf(float f) {
  unsigned int u = __builtin_bit_cast(unsigned int, f);
  u = (u + 0x7FFFu + ((u >> 16) & 1u)) >> 16;
  return (USH)u;
}

// packed RNE f32x2 -> bf16x2 via official HIP intrinsic (verified r9/r12/r13/r15/r17)
__device__ __forceinline__ uint32 pkbf2(float lo, float hi) {
  __hip_bfloat162 h2 = __float22bfloat162_rn(float2{lo, hi});
  uint32 r;
  __builtin_memcpy(&r, &h2, 4);
  return r;
}

__device__ __forceinline__ f32x4 mfma16(short8 a, short8 b, f32x4 c) {
  return __builtin_amdgcn_mfma_f32_16x16x32_bf16(a, b, c, 0, 0, 0);
}

// 16x16x16 bf16 MFMA (legacy K=16 shape; A/B = 4 bf16/lane at k = (lane>>4)*4+e)
__device__ __forceinline__ f32x4 mfma16h(short4v a, short4v b, f32x4 c) {
#if __has_builtin(__builtin_amdgcn_mfma_f32_16x16x16bf16_1k)
  return __builtin_amdgcn_mfma_f32_16x16x16bf16_1k(a, b, c, 0, 0, 0);
#else
  f32x4 d;
  asm volatile("v_mfma_f32_16x16x16_bf16 %0, %1, %2, %3"
               : "=&v"(d)
               : "v"(a), "v"(b), "v"(c));
  return d;
#endif
}

// async global->LDS, 16B per lane, dest = base + lane*16 (linear)
__device__ __forceinline__ void gload16(const USH* g, USH* l) {
  __builtin_amdgcn_global_load_lds(
      (const __attribute__((address_space(1))) unsigned int*)g,
      (__attribute__((address_space(3))) unsigned int*)l, 16, 0, 0);
}

__device__ __forceinline__ f32x4 vmax4(f32x4 a, f32x4 b) {
  f32x4 r;
  r[0] = fmaxf(a[0], b[0]);
  r[1] = fmaxf(a[1], b[1]);
  r[2] = fmaxf(a[2], b[2]);
  r[3] = fmaxf(a[3], b[3]);
  return r;
}

union Frag4 {
  uint32 u[2];
  short4v s4;
};

// ---------------- fp32 -> bf16 convert (all three inputs, one launch) ----------------
__global__ __launch_bounds__(256) void cvt_all(const float* __restrict__ x,
                                               const float* __restrict__ w_in,
                                               const float* __restrict__ w_out,
                                               USH* __restrict__ xb,
                                               USH* __restrict__ winb,
                                               USH* __restrict__ woutb) {
  const int bid = blockIdx.x;
  const float* src;
  USH* dst;
  int i;
  if (bid < 8192) {
    src = x;
    dst = xb;
    i = bid * 256 + threadIdx.x;
  } else if (bid < 8960) {
    src = w_in;
    dst = winb;
    i = (bid - 8192) * 256 + threadIdx.x;
  } else {
    src = w_out;
    dst = woutb;
    i = (bid - 8960) * 256 + threadIdx.x;
  }
  f32x4 v = *(const f32x4*)(src + (size_t)i * 4);
  ushort4v o;
#pragma unroll
  for (int k = 0; k < 4; k++) o[k] = f2bf(v[k]);
  *(ushort4v*)(dst + (size_t)i * 4) = o;
}

// ---------------- GEMM: C[M,N] = A[M,K] @ B[N,K]^T + bias ----------------
// OUT_F32=false (gemm1): blocks with col0>=1024 (the V third) write DIRECTLY
// TRANSPOSED into vT[bh][dh][s] instead of qkv — vtrans kernel eliminated.
template <bool OUT_F32>
__global__ __launch_bounds__(256) void gemm_bt(const USH* __restrict__ A,
                                               const USH* __restrict__ B,
                                               const float* __restrict__ bias,
                                               void* __restrict__ Cout,
                                               USH* __restrict__ vT,
                                               int M, int N, int K) {
  __shared__ __align__(16) USH As[128 * 64];
  __shared__ __align__(16) USH Bs[128 * 64];
  const int tid = threadIdx.x;
  const int row0 = blockIdx.x * 128;
  const int col0 = blockIdx.y * 128;
  const int wid = tid >> 6, lane = tid & 63;
  const int wr = (wid >> 1) * 64, wc = (wid & 1) * 64;
  const int lmod = lane & 15, ldiv = lane >> 4;
  const int asw = lmod & 7;
  const int srow = lane >> 3;
  const int scol = ((lane & 7) ^ srow) * 8;

  f32x4 acc[4][4];
#pragma unroll
  for (int i = 0; i < 4; i++)
#pragma unroll
    for (int j = 0; j < 4; j++) acc[i][j] = (f32x4){0.f, 0.f, 0.f, 0.f};

  const USH* Ab = A + (size_t)row0 * K;
  const USH* Bb = B + (size_t)col0 * K;

  for (int k0 = 0; k0 < K; k0 += 64) {
    __syncthreads();
#pragma unroll
    for (int i = 0; i < 4; i++) {
      int r0 = wid * 32 + i * 8;
      int r = r0 + srow;
      gload16(&Ab[(size_t)r * K + k0 + scol], &As[r0 * 64]);
      gload16(&Bb[(size_t)r * K + k0 + scol], &Bs[r0 * 64]);
    }
    __syncthreads();
#pragma unroll
    for (int kk = 0; kk < 64; kk += 32) {
      short8 a[4], b[4];
#pragma unroll
      for (int i = 0; i < 4; i++)
        a[i] = *(const short8*)&As[(wr + i * 16 + lmod) * 64 +
                                   ((((kk >> 3) + ldiv) ^ asw) << 3)];
#pragma unroll
      for (int i = 0; i < 4; i++)
        b[i] = *(const short8*)&Bs[(wc + i * 16 + lmod) * 64 +
                                   ((((kk >> 3) + ldiv) ^ asw) << 3)];
#pragma unroll
      for (int i = 0; i < 4; i++)
#pragma unroll
        for (int j = 0; j < 4; j++)
          acc[i][j] = mfma16(a[i], b[j], acc[i][j]);
    }
  }

  const int r4 = ldiv * 4;
  const bool vpart = (!OUT_F32) && (col0 >= 1024);
#pragma unroll
  for (int i = 0; i < 4; i++) {
#pragma unroll
    for (int j = 0; j < 4; j++) {
      int rr = row0 + wr + i * 16 + r4;
      int cc = col0 + wc + j * 16 + lmod;
      float bv = bias[cc];
      if (OUT_F32) {
#pragma unroll
        for (int t = 0; t < 4; t++)
          ((float*)Cout)[(size_t)(rr + t) * N + cc] = acc[i][j][t] + bv;
      } else if (vpart) {
        // transposed V write: vT[(b*8+h)*64 + dh][s], s = rr..rr+3 (8B contiguous)
        const int hc = cc - 1024;
        const int bb = rr >> 12, s = rr & 4095;
        ushort4v o;
#pragma unroll
        for (int t = 0; t < 4; t++) o[t] = f2bf(acc[i][j][t] + bv);
        *(ushort4v*)&vT[((size_t)(bb * 8 + (hc >> 6)) * 64 + (hc & 63)) * 4096 + s] = o;
      } else {
#pragma unroll
        for (int t = 0; t < 4; t++)
          ((USH*)Cout)[(size_t)(rr + t) * N + cc] = f2bf(acc[i][j][t] + bv);
      }
    }
  }
}

// ---------------- Flash attention v21 == v17 (best verified: 195.5 us) ----------------
__global__ __launch_bounds__(256, 4) void attn_fwd(const USH* __restrict__ qkv,
                                                   const USH* __restrict__ vT,
                                                   USH* __restrict__ attno) {
  __shared__ __align__(16) USH Ks[2][64 * 64];   // 16 KB
  __shared__ __align__(16) USH Vs[2][64 * 64];   // 16 KB

  const int fb = blockIdx.x;
  const int b3 = fb & 7;
  const int rest = fb >> 3;
  const int qb = rest & 31;
  const int bh = b3 + 8 * (rest >> 5);
  const int b = bh >> 3, h = bh & 7;

  const int wid = threadIdx.x >> 6, lane = threadIdx.x & 63;
  const int lmod = lane & 15, ldiv = lane >> 4;
  const int ksw = lmod & 7;
  const int qrow0 = qb * 128 + wid * 32;

  short8 qf00, qf01, qf10, qf11;
  {
    const USH* qp = qkv + (size_t)(b * 4096 + qrow0 + lmod) * 1536 + h * 64 + ldiv * 8;
    qf00 = *(const short8*)qp;
    qf01 = *(const short8*)(qp + 32);
    qp += (size_t)16 * 1536;
    qf10 = *(const short8*)qp;
    qf11 = *(const short8*)(qp + 32);
  }

  short4v ones4;
#pragma unroll
  for (int i = 0; i < 4; i++) ones4[i] = (short)0x3F80;  // bf16 1.0

  f32x4 acc0[4], acc1[4];
#pragma unroll
  for (int n = 0; n < 4; n++) {
    acc0[n] = (f32x4){0.f, 0.f, 0.f, 0.f};
    acc1[n] = (f32x4){0.f, 0.f, 0.f, 0.f};
  }
  f32x4 l0 = (f32x4){0.f, 0.f, 0.f, 0.f}, l1 = l0;
  float nmk0 = 0.f, nmk1 = 0.f;  // -m*K2, m fixed from tile 0 (r17-verified exact)
  const f32x4 z4 = (f32x4){0.f, 0.f, 0.f, 0.f};

  const USH* kbase = qkv + (size_t)b * 4096 * 1536 + 512 + h * 64;
  const USH* vbase = vT + (size_t)bh * 64 * 4096;
  const int srow = lane >> 3;
  const int scol = ((lane & 7) ^ srow) * 8;  // K source swizzle (8-group, row&7)
  const float K2 = 0.18033688011112042f;     // log2(e)/8

  auto stage = [&](int bu, int k0) {
#pragma unroll
    for (int i = 0; i < 2; ++i) {
      int r0 = wid * 16 + i * 8;
      int r = r0 + srow;
      gload16(kbase + (size_t)(k0 + r) * 1536 + scol, &Ks[bu][r0 * 64]);
      int vsw = ((2 * (lane & 7)) ^ (r & 14)) * 4;
      gload16(vbase + (size_t)r * 4096 + k0 + vsw, &Vs[bu][r0 * 64]);
    }
  };

  stage(0, 0);

  for (int t = 0; t < 64; ++t) {
    const int cur = t & 1;
    __syncthreads();
    if (t < 63) stage(cur ^ 1, (t + 1) * 64);

    const USH* Kc = &Ks[cur][0];
    const USH* Vc = &Vs[cur][0];

    // ---- QK^T swapped: s{0,1}[n][j] -> q = lmod, kv = n*16 + ldiv*4 + j ----
    f32x4 s0[4], s1[4];
    __builtin_amdgcn_s_setprio(1);
#pragma unroll
    for (int n = 0; n < 4; n++) {
      const USH* kr = Kc + (n * 16 + lmod) * 64;
      short8 kf0 = *(const short8*)(kr + ((ldiv ^ ksw) << 3));
      short8 kf1 = *(const short8*)(kr + (((4 + ldiv) ^ ksw) << 3));
      s0[n] = mfma16(kf0, qf00, z4);
      s0[n] = mfma16(kf1, qf01, s0[n]);
      s1[n] = mfma16(kf0, qf10, z4);
      s1[n] = mfma16(kf1, qf11, s1[n]);
    }
    __builtin_amdgcn_s_setprio(0);

    // ---- m fixed at tile 0 (full row-max); exact (m-invariant math, r17) ----
    if (t == 0) {
      f32x4 u0 = vmax4(vmax4(s0[0], s0[1]), vmax4(s0[2], s0[3]));
      float p0 = fmaxf(fmaxf(u0[0], u0[1]), fmaxf(u0[2], u0[3]));
      p0 = fmaxf(p0, __shfl_xor(p0, 16));
      p0 = fmaxf(p0, __shfl_xor(p0, 32));
      f32x4 u1 = vmax4(vmax4(s1[0], s1[1]), vmax4(s1[2], s1[3]));
      float p1 = fmaxf(fmaxf(u1[0], u1[1]), fmaxf(u1[2], u1[3]));
      p1 = fmaxf(p1, __shfl_xor(p1, 16));
      p1 = fmaxf(p1, __shfl_xor(p1, 32));
      nmk0 = -p0 * K2;
      nmk1 = -p1 * K2;
    }

    // ---- P in-register -> 16x16x16 PV (+ rowsum); V fragment shared by both groups ----
#pragma unroll
    for (int n = 0; n < 4; n++) {
      Frag4 pa0, pa1;
      {
        float e0 = __builtin_amdgcn_exp2f(fmaf(s0[n][0], K2, nmk0));
        float e1 = __builtin_amdgcn_exp2f(fmaf(s0[n][1], K2, nmk0));
        float e2 = __builtin_amdgcn_exp2f(fmaf(s0[n][2], K2, nmk0));
        float e3 = __builtin_amdgcn_exp2f(fmaf(s0[n][3], K2, nmk0));
        pa0.u[0] = pkbf2(e0, e1);
        pa0.u[1] = pkbf2(e2, e3);
      }
      {
        float e0 = __builtin_amdgcn_exp2f(fmaf(s1[n][0], K2, nmk1));
        float e1 = __builtin_amdgcn_exp2f(fmaf(s1[n][1], K2, nmk1));
        float e2 = __builtin_amdgcn_exp2f(fmaf(s1[n][2], K2, nmk1));
        float e3 = __builtin_amdgcn_exp2f(fmaf(s1[n][3], K2, nmk1));
        pa1.u[0] = pkbf2(e0, e1);
        pa1.u[1] = pkbf2(e2, e3);
      }
      __builtin_amdgcn_s_setprio(1);
      l0 = mfma16h(pa0.s4, ones4, l0);
      l1 = mfma16h(pa1.s4, ones4, l1);
#pragma unroll
      for (int n2 = 0; n2 < 4; n2++) {
        const int vcol = (((n * 4 + ldiv) ^ (lmod & 14)) << 2);
        short4v vf = *(const short4v*)(Vc + (n2 * 16 + lmod) * 64 + vcol);
        acc0[n2] = mfma16h(pa0.s4, vf, acc0[n2]);
        acc1[n2] = mfma16h(pa1.s4, vf, acc1[n2]);
      }
      __builtin_amdgcn_s_setprio(0);
    }
  }

  // ---- epilogue (acc layout: q = ldiv*4+j, dh = n*16+lmod) ----
  float iv0[4], iv1[4];
#pragma unroll
  for (int j = 0; j < 4; j++) {
    iv0[j] = 1.0f / l0[j];
    iv1[j] = 1.0f / l1[j];
  }
  USH* ob = attno + (size_t)(b * 4096 + qrow0) * 512 + h * 64;
#pragma unroll
  for (int n = 0; n < 4; n++) {
#pragma unroll
    for (int j = 0; j < 4; j++) {
      ob[(size_t)(ldiv * 4 + j) * 512 + n * 16 + lmod] = f2bf(acc0[n][j] * iv0[j]);
      ob[(size_t)(16 + ldiv * 4 + j) * 512 + n * 16 + lmod] = f2bf(acc1[n][j] * iv1[j]);
    }
  }
}

// ---------------- launch ----------------
extern "C" void kernel_launch(void* const* d_in, const int* in_sizes, int n_in,
                              void* d_out, int out_size, void* d_ws, size_t ws_size,
                              hipStream_t stream) {
  const float* x = (const float*)d_in[0];      // (4,4096,512)
  const float* w_in = (const float*)d_in[1];   // (1536,512)
  const float* b_in = (const float*)d_in[2];   // (1536)
  const float* w_out = (const float*)d_in[3];  // (512,512)
  const float* b_out = (const float*)d_in[4];  // (512)
  float* out = (float*)d_out;                  // (4,4096,512) fp32

  char* ws = (char*)d_ws;
  USH* xb = (USH*)(ws);                        // 16 MB (reused as attno later)
  USH* winb = (USH*)(ws + 16777216);           // 1.5 MB
  USH* woutb = (USH*)(ws + 18350080);          // 0.5 MB
  USH* qkv = (USH*)(ws + 18874368);            // 48 MB (V third unused)
  USH* vT = (USH*)(ws + 69206016);             // 16 MB
  USH* attno = xb;                             // alias: xb dead after gemm1

  cvt_all<<<9216, 256, 0, stream>>>(x, w_in, w_out, xb, winb, woutb);

  gemm_bt<false><<<dim3(128, 12), 256, 0, stream>>>(xb, winb, b_in, qkv, vT,
                                                    16384, 1536, 512);
  attn_fwd<<<1024, 256, 0, stream>>>(qkv, vT, attno);
  gemm_bt<true><<<dim3(128, 4), 256, 0, stream>>>(attno, woutb, b_out, out, nullptr,
                                                  16384, 512, 512);
}